// Round 3
// baseline (127.649 us; speedup 1.0000x reference)
//
#include <hip/hip_runtime.h>
#include <hip/hip_fp16.h>
#include <math.h>
#include <stdint.h>

#define FDIM 1024
#define BTOT 16384
#define EDIM 64
#define NFLD 32
#define KS 32   // k-splits for gram: 512 batch rows per block

typedef _Float16 half8 __attribute__((ext_vector_type(8)));
typedef float f32x4 __attribute__((ext_vector_type(4)));

// XOR swizzle of the low-3 column bits by the next-3 bits; baked into the
// GLOBAL chunk layout (written by the transpose path) AND the LDS read
// addressing in gram_mfma (both-sides rule: global_load_lds writes linearly).
__device__ __forceinline__ int swz(int c){ return (c & ~7) | ((c ^ (c >> 3)) & 7); }

__device__ __forceinline__ uint32_t pkh(float a, float b){
  _Float16 lo = (_Float16)a, hi = (_Float16)b;
  uint16_t ulo = __builtin_bit_cast(uint16_t, lo);
  uint16_t uhi = __builtin_bit_cast(uint16_t, hi);
  return ((uint32_t)uhi << 16) | (uint32_t)ulo;
}

__device__ __forceinline__ void gload16(const void* g, void* l){
  __builtin_amdgcn_global_load_lds((const __attribute__((address_space(1))) void*)g,
                                   (__attribute__((address_space(3))) void*)l,
                                   16, 0, 0);
}

// ---------------------------------------------------------------------------
// prep: bucket feature indices by field. grp[33] offsets, perm[1024] members.
// ---------------------------------------------------------------------------
__global__ void prep_groups(const int* __restrict__ fields, int* __restrict__ grp,
                            int* __restrict__ perm){
  __shared__ int cnt[NFLD];
  __shared__ int pos[NFLD];
  const int t = threadIdx.x;
  if (t < NFLD) cnt[t] = 0;
  __syncthreads();
  const int f = fields[t];
  atomicAdd(&cnt[f], 1);
  __syncthreads();
  if (t == 0){
    int s = 0;
    for (int i = 0; i < NFLD; ++i){ grp[i] = s; pos[i] = s; s += cnt[i]; }
    grp[NFLD] = s;
  }
  __syncthreads();
  const int p = atomicAdd(&pos[f], 1);
  perm[p] = t;
}

// ---------------------------------------------------------------------------
// mid_fused: blockIdx.x < 1024  -> W2 path (field-pair GEMM-let for A matrix)
//            blockIdx.x >= 1024 -> transpose path (X f32 -> swizzled fp16
//                                  chunk layout) + fused linear term.
// W2 is latency-bound, transpose is HBM-bound: co-residency overlaps them.
// ---------------------------------------------------------------------------
__global__ __launch_bounds__(256) void mid_fused(
    const float* __restrict__ vs, const int* __restrict__ grp,
    const int* __restrict__ perm, float* __restrict__ W,
    const float* __restrict__ X, const float* __restrict__ w,
    uint4* __restrict__ Xbt, float* __restrict__ lin){
  __shared__ float Si[64][68];
  __shared__ float Sj[64][68];
  __shared__ int gI[64], gJ[64];
  const int t = threadIdx.x;

  if (blockIdx.x >= 1024){
    // ------------------- transpose + linear path -------------------
    const int bx = blockIdx.x - 1024;
    const int p  = bx & 7;
    const int kb = bx >> 3;
    const int q  = t & 31;        // col quad within panel
    const int ro = t >> 5;        // row oct 0..7
    const int k0 = kb * 64 + ro * 8;
    const int c0 = p * 128 + q * 4;

    float xs[8][4];
#pragma unroll
    for (int r = 0; r < 8; ++r){
      const float4 v = *(const float4*)(X + (size_t)(k0 + r) * FDIM + c0);
      xs[r][0] = v.x; xs[r][1] = v.y; xs[r][2] = v.z; xs[r][3] = v.w;
    }

    const float4 w4 = *(const float4*)(w + c0);
#pragma unroll
    for (int r = 0; r < 8; ++r){
      float lp = xs[r][0] * w4.x + xs[r][1] * w4.y + xs[r][2] * w4.z + xs[r][3] * w4.w;
#pragma unroll
      for (int off = 16; off; off >>= 1) lp += __shfl_xor(lp, off, 64);
      if (q == 0) atomicAdd(&lin[k0 + r], lp);
    }

    const int og = kb * 8 + ro;  // global k-oct
    uint4* dst = Xbt + ((size_t)p * 2048 + og) * 128;
#pragma unroll
    for (int i = 0; i < 4; ++i){
      uint4 ch;
      ch.x = pkh(xs[0][i], xs[1][i]);
      ch.y = pkh(xs[2][i], xs[3][i]);
      ch.z = pkh(xs[4][i], xs[5][i]);
      ch.w = pkh(xs[6][i], xs[7][i]);
      dst[swz(q * 4 + i)] = ch;
    }
    return;
  }

  // ------------------- W2 path -------------------
  const int a = blockIdx.x >> 5, b = blockIdx.x & 31;
  const int oa = grp[a], na = grp[a + 1] - oa;
  const int ob = grp[b], nb = grp[b + 1] - ob;
  if (na == 0 || nb == 0) return;
  for (int ia0 = 0; ia0 < na; ia0 += 64){
    const int nac = min(64, na - ia0);
    for (int jb0 = 0; jb0 < nb; jb0 += 64){
      const int nbc = min(64, nb - jb0);
      __syncthreads();
      if (t < 64){
        gI[t] = (t < nac) ? perm[oa + ia0 + t] : 0;
        gJ[t] = (t < nbc) ? perm[ob + jb0 + t] : 0;
      }
      __syncthreads();
#pragma unroll
      for (int rep = 0; rep < 4; ++rep){
        const int lidx = rep * 256 + t;
        const int r = lidx >> 4, e4 = (lidx & 15) * 4;
        if (r < nac)
          *(float4*)&Si[r][e4] = *(const float4*)(vs + ((size_t)b * FDIM + gI[r]) * EDIM + e4);
        if (r < nbc)
          *(float4*)&Sj[r][e4] = *(const float4*)(vs + ((size_t)a * FDIM + gJ[r]) * EDIM + e4);
      }
      __syncthreads();
      const int jr = t & 63;
      for (int ko = 0; ko * 4 < nac; ++ko){
        const int ir = ko * 4 + (t >> 6);
        if (ir < nac && jr < nbc){
          float dot = 0.f;
#pragma unroll
          for (int e4 = 0; e4 < EDIM; e4 += 4){
            const float4 x = *(const float4*)&Si[ir][e4];
            const float4 y = *(const float4*)&Sj[jr][e4];
            dot += x.x * y.x + x.y * y.y + x.z * y.z + x.w * y.w;
          }
          const int gi = gI[ir], gj = gJ[jr];
          W[(size_t)gi * FDIM + gj] = (gj > gi) ? dot : 0.f;
        }
      }
    }
  }
}

// ---------------------------------------------------------------------------
// gram_mfma: upper-tri 128x128 tile pairs (36) x KS k-splits.
// Double-buffered 2-phase pipeline (T3 minimum recipe): STAGE(next) before
// compute(current), one barrier per 32-row stage. Epilogue dots P-tile with
// W tile, wave-reduce, atomicAdd scalar.
// ---------------------------------------------------------------------------
__global__ __launch_bounds__(256) void gram_mfma(
    const uint4* __restrict__ Xbt, const float* __restrict__ W,
    float* __restrict__ s_out){
  int pp = blockIdx.x, ti = 0, rem = 8;
  while (pp >= rem){ pp -= rem; ++ti; --rem; }
  const int tj = ti + pp;
  const int ko0 = blockIdx.y * (2048 / KS);   // 64 octs (512 rows) per block

  __shared__ uint4 lds[2][1024];   // per buf: A slice 512 chunks | B slice 512
  const int t = threadIdx.x, w = t >> 6, lane = t & 63;
  const int m0 = (w >> 1) * 64, n0 = (w & 1) * 64;
  const int orow = lane >> 4, rl = lane & 15;

  const uint4* gA = Xbt + ((size_t)ti * 2048 + ko0) * 128;
  const uint4* gB = Xbt + ((size_t)tj * 2048 + ko0) * 128;

  f32x4 acc[4][4];
#pragma unroll
  for (int i = 0; i < 4; ++i)
#pragma unroll
    for (int j = 0; j < 4; ++j) acc[i][j] = {0.f, 0.f, 0.f, 0.f};

  int swA[4], swB[4];
#pragma unroll
  for (int mb = 0; mb < 4; ++mb) swA[mb] = swz(m0 + mb * 16 + rl);
#pragma unroll
  for (int nb = 0; nb < 4; ++nb) swB[nb] = 512 + swz(n0 + nb * 16 + rl);

  // stage st (4 octs = 32 batch rows): 512 A-chunks + 512 B-chunks
#define STAGE(buf, st)                                                        \
  {                                                                           \
    _Pragma("unroll")                                                         \
    for (int n = 0; n < 2; ++n){                                              \
      const int grp_ = w * 2 + n;                                             \
      gload16(gA + (size_t)(st) * 512 + grp_ * 64 + lane,                     \
              &lds[buf][grp_ * 64]);                                          \
      gload16(gB + (size_t)(st) * 512 + grp_ * 64 + lane,                     \
              &lds[buf][512 + grp_ * 64]);                                    \
    }                                                                         \
  }

  STAGE(0, 0);
  __syncthreads();

  const int NST = 2048 / KS / 4;   // 16 stages
  for (int st = 0; st < NST; ++st){
    const int cur = st & 1;
    if (st + 1 < NST) STAGE(cur ^ 1, st + 1);

    const uint4* L = lds[cur];
    half8 af[4], bf[4];
#pragma unroll
    for (int mb = 0; mb < 4; ++mb) af[mb] = __builtin_bit_cast(half8, L[orow * 128 + swA[mb]]);
#pragma unroll
    for (int nb = 0; nb < 4; ++nb) bf[nb] = __builtin_bit_cast(half8, L[orow * 128 + swB[nb]]);
#pragma unroll
    for (int mb = 0; mb < 4; ++mb)
#pragma unroll
      for (int nb = 0; nb < 4; ++nb)
        acc[mb][nb] = __builtin_amdgcn_mfma_f32_16x16x32_f16(af[mb], bf[nb], acc[mb][nb], 0, 0, 0);

    __syncthreads();  // drains lgkm (our reads) + vmcnt (prefetch) pre-barrier
  }
#undef STAGE

  // epilogue: dot with W tile (W zero for j<=i masks the diagonal tiles)
  const int i0 = ti * 128 + m0, j0 = tj * 128 + n0;
  float part = 0.f;
#pragma unroll
  for (int mb = 0; mb < 4; ++mb){
#pragma unroll
    for (int r = 0; r < 4; ++r){
      const int gi = i0 + mb * 16 + orow * 4 + r;
      const float* Wr = W + (size_t)gi * FDIM + j0 + rl;
#pragma unroll
      for (int nb = 0; nb < 4; ++nb)
        part += acc[mb][nb][r] * Wr[nb * 16];
    }
  }
#pragma unroll
  for (int off = 32; off; off >>= 1) part += __shfl_xor(part, off, 64);
  if (lane == 0) atomicAdd(s_out, part);
}

// ---------------------------------------------------------------------------
__global__ void final_out(const float* __restrict__ lin, const float* __restrict__ wb,
                          const float* __restrict__ s, float* __restrict__ out){
  const int i = blockIdx.x * 256 + threadIdx.x;
  const float z = lin[i] + wb[0] + s[0];
  out[i] = 1.f / (1.f + expf(-z));
}

// ---------------------------------------------------------------------------
extern "C" void kernel_launch(void* const* d_in, const int* in_sizes, int n_in,
                              void* d_out, int out_size, void* d_ws,
                              size_t ws_size, hipStream_t stream) {
  const float* X      = (const float*)d_in[0];  // [B, F]
  const int* fields   = (const int*)d_in[1];    // [F]
  const float* ww     = (const float*)d_in[2];  // [1, F]
  const float* wbias  = (const float*)d_in[3];  // [1]
  const float* vs     = (const float*)d_in[4];  // [NF, F, E]
  float* out          = (float*)d_out;          // [B, 1]

  char* ws = (char*)d_ws;
  float* s_acc = (float*)ws;                       // 4 B scalar
  float* lin   = (float*)(ws + 1024);              // 64 KB
  int* grp     = (int*)(ws + 1024 + 65536);        // 33 ints
  int* perm    = (int*)(ws + 1024 + 65536 + 256);  // 4 KB
  float* W     = (float*)(ws + (size_t)(4 << 20)); // 4 MB at 4 MB offset
  uint4* Xbt   = (uint4*)(ws + (size_t)(8 << 20)); // 32 MB at 8 MB offset

  hipMemsetAsync(ws, 0, 1024 + 65536, stream);     // s_acc + lin

  prep_groups<<<1, 1024, 0, stream>>>(fields, grp, perm);
  mid_fused<<<1024 + 2048, 256, 0, stream>>>(vs, grp, perm, W, X, ww, Xbt, lin);
  gram_mfma<<<dim3(36, KS), 256, 0, stream>>>(Xbt, W, s_acc);
  final_out<<<64, 256, 0, stream>>>(lin, wbias, s_acc, out);
}

// Round 4
// 93.491 us; speedup vs baseline: 1.3654x; 1.3654x over previous
//
#include <hip/hip_runtime.h>
#include <hip/hip_fp16.h>
#include <math.h>
#include <stdint.h>

#define FDIM 1024
#define BTOT 16384
#define EDIM 64
#define NFLD 32
#define KS 32        // k-splits for gram: 512 batch rows per block
#define NST 16       // stages per block: 4 k-octs (32 rows) each

typedef _Float16 half8 __attribute__((ext_vector_type(8)));
typedef float f32x4 __attribute__((ext_vector_type(4)));

// XOR swizzle baked into the GLOBAL chunk layout (written by the transpose
// path) AND the LDS read addressing in gram_mfma (both-sides rule:
// global_load_lds writes its LDS destination linearly).
__device__ __forceinline__ int swz(int c){ return (c & ~7) | ((c ^ (c >> 3)) & 7); }

__device__ __forceinline__ uint32_t pkh(float a, float b){
  _Float16 lo = (_Float16)a, hi = (_Float16)b;
  uint16_t ulo = __builtin_bit_cast(uint16_t, lo);
  uint16_t uhi = __builtin_bit_cast(uint16_t, hi);
  return ((uint32_t)uhi << 16) | (uint32_t)ulo;
}

__device__ __forceinline__ void gload16(const void* g, void* l){
  __builtin_amdgcn_global_load_lds((const __attribute__((address_space(1))) void*)g,
                                   (__attribute__((address_space(3))) void*)l,
                                   16, 0, 0);
}

// ---------------------------------------------------------------------------
// prep: bucket feature indices by field. grp[33] offsets, perm[1024] members.
// ---------------------------------------------------------------------------
__global__ void prep_groups(const int* __restrict__ fields, int* __restrict__ grp,
                            int* __restrict__ perm){
  __shared__ int cnt[NFLD];
  __shared__ int pos[NFLD];
  const int t = threadIdx.x;
  if (t < NFLD) cnt[t] = 0;
  __syncthreads();
  const int f = fields[t];
  atomicAdd(&cnt[f], 1);
  __syncthreads();
  if (t == 0){
    int s = 0;
    for (int i = 0; i < NFLD; ++i){ grp[i] = s; pos[i] = s; s += cnt[i]; }
    grp[NFLD] = s;
  }
  __syncthreads();
  const int p = atomicAdd(&pos[f], 1);
  perm[p] = t;
}

// ---------------------------------------------------------------------------
// mid_fused: blockIdx.x < 1024  -> W2 path (field-pair GEMM-let for A matrix)
//            blockIdx.x >= 1024 -> transpose path (X f32 -> swizzled fp16
//                                  chunk layout) + linear-term partials.
// ---------------------------------------------------------------------------
__global__ __launch_bounds__(256) void mid_fused(
    const float* __restrict__ vs, const int* __restrict__ grp,
    const int* __restrict__ perm, float* __restrict__ W,
    const float* __restrict__ X, const float* __restrict__ w,
    uint4* __restrict__ Xbt, float* __restrict__ linp){
  __shared__ float Si[64][68];
  __shared__ float Sj[64][68];
  __shared__ int gI[64], gJ[64];
  const int t = threadIdx.x;

  if (blockIdx.x >= 1024){
    // ------------------- transpose + linear path -------------------
    const int bx = blockIdx.x - 1024;
    const int p  = bx & 7;
    const int kb = bx >> 3;
    const int q  = t & 31;        // col quad within panel
    const int ro = t >> 5;        // row oct 0..7
    const int k0 = kb * 64 + ro * 8;
    const int c0 = p * 128 + q * 4;

    float xs[8][4];
#pragma unroll
    for (int r = 0; r < 8; ++r){
      const float4 v = *(const float4*)(X + (size_t)(k0 + r) * FDIM + c0);
      xs[r][0] = v.x; xs[r][1] = v.y; xs[r][2] = v.z; xs[r][3] = v.w;
    }

    const float4 w4 = *(const float4*)(w + c0);
#pragma unroll
    for (int r = 0; r < 8; ++r){
      float lp = xs[r][0] * w4.x + xs[r][1] * w4.y + xs[r][2] * w4.z + xs[r][3] * w4.w;
#pragma unroll
      for (int off = 16; off; off >>= 1) lp += __shfl_xor(lp, off, 64);
      if (q == 0) linp[(size_t)p * BTOT + k0 + r] = lp;  // no atomics
    }

    const int og = kb * 8 + ro;  // global k-oct
    uint4* dst = Xbt + ((size_t)p * 2048 + og) * 128;
#pragma unroll
    for (int i = 0; i < 4; ++i){
      uint4 ch;
      ch.x = pkh(xs[0][i], xs[1][i]);
      ch.y = pkh(xs[2][i], xs[3][i]);
      ch.z = pkh(xs[4][i], xs[5][i]);
      ch.w = pkh(xs[6][i], xs[7][i]);
      dst[swz(q * 4 + i)] = ch;
    }
    return;
  }

  // ------------------- W2 path -------------------
  const int a = blockIdx.x >> 5, b = blockIdx.x & 31;
  const int oa = grp[a], na = grp[a + 1] - oa;
  const int ob = grp[b], nb = grp[b + 1] - ob;
  if (na == 0 || nb == 0) return;
  for (int ia0 = 0; ia0 < na; ia0 += 64){
    const int nac = min(64, na - ia0);
    for (int jb0 = 0; jb0 < nb; jb0 += 64){
      const int nbc = min(64, nb - jb0);
      __syncthreads();
      if (t < 64){
        gI[t] = (t < nac) ? perm[oa + ia0 + t] : 0;
        gJ[t] = (t < nbc) ? perm[ob + jb0 + t] : 0;
      }
      __syncthreads();
#pragma unroll
      for (int rep = 0; rep < 4; ++rep){
        const int lidx = rep * 256 + t;
        const int r = lidx >> 4, e4 = (lidx & 15) * 4;
        if (r < nac)
          *(float4*)&Si[r][e4] = *(const float4*)(vs + ((size_t)b * FDIM + gI[r]) * EDIM + e4);
        if (r < nbc)
          *(float4*)&Sj[r][e4] = *(const float4*)(vs + ((size_t)a * FDIM + gJ[r]) * EDIM + e4);
      }
      __syncthreads();
      const int jr = t & 63;
      for (int ko = 0; ko * 4 < nac; ++ko){
        const int ir = ko * 4 + (t >> 6);
        if (ir < nac && jr < nbc){
          float dot = 0.f;
#pragma unroll
          for (int e4 = 0; e4 < EDIM; e4 += 4){
            const float4 x = *(const float4*)&Si[ir][e4];
            const float4 y = *(const float4*)&Sj[jr][e4];
            dot += x.x * y.x + x.y * y.y + x.z * y.z + x.w * y.w;
          }
          const int gi = gI[ir], gj = gJ[jr];
          W[(size_t)gi * FDIM + gj] = (gj > gi) ? dot : 0.f;
        }
      }
    }
  }
}

// ---------------------------------------------------------------------------
// gram_mfma: upper-tri 128x128 tile pairs (36) x KS k-splits.
// Depth-2 counted-vmcnt pipeline (T3+T4): 3 LDS buffers, per-stage
//   s_waitcnt vmcnt(4) -> s_barrier -> issue STAGE(t+2) -> ds_read+MFMA(t).
// Safety: vmcnt(4) proves THIS wave's stage-t loads landed; the barrier then
// proves EVERY wave's stage-t loads landed (all of stage t is in LDS) before
// any ds_read. STAGE(t+2) overwrites buf (t-1)%3 only after the barrier that
// proves all waves finished reading it in iter t-1. vmcnt never drains to 0
// mid-loop. Epilogue writes per-wave partials (no same-address atomics).
// ---------------------------------------------------------------------------
__global__ __launch_bounds__(256) void gram_mfma(
    const uint4* __restrict__ Xbt, const float* __restrict__ W,
    float* __restrict__ partial){
  int pp = blockIdx.x, ti = 0, rem = 8;
  while (pp >= rem){ pp -= rem; ++ti; --rem; }
  const int tj = ti + pp;
  const int ko0 = blockIdx.y * (2048 / KS);   // 64 octs (512 rows) per block

  __shared__ uint4 lds[3][1024];   // per buf 16KB: A slice 512 | B slice 512
  const int t = threadIdx.x, w = t >> 6, lane = t & 63;
  const int m0 = (w >> 1) * 64, n0 = (w & 1) * 64;
  const int orow = lane >> 4, rl = lane & 15;

  const uint4* gA = Xbt + ((size_t)ti * 2048 + ko0) * 128;
  const uint4* gB = Xbt + ((size_t)tj * 2048 + ko0) * 128;

  f32x4 acc[4][4];
#pragma unroll
  for (int i = 0; i < 4; ++i)
#pragma unroll
    for (int j = 0; j < 4; ++j) acc[i][j] = {0.f, 0.f, 0.f, 0.f};

  int swA[4], swB[4];
#pragma unroll
  for (int mb = 0; mb < 4; ++mb) swA[mb] = swz(m0 + mb * 16 + rl);
#pragma unroll
  for (int nb = 0; nb < 4; ++nb) swB[nb] = 512 + swz(n0 + nb * 16 + rl);

  // stage st (4 octs = 32 batch rows): 512 A-chunks + 512 B-chunks;
  // 4 gload16 per wave per stage (vmcnt counts 4/stage/wave).
#define STAGE(buf, st)                                                        \
  {                                                                           \
    _Pragma("unroll")                                                         \
    for (int n = 0; n < 2; ++n){                                              \
      const int grp_ = w * 2 + n;                                             \
      gload16(gA + (size_t)(st) * 512 + grp_ * 64 + lane,                     \
              &lds[buf][grp_ * 64]);                                          \
      gload16(gB + (size_t)(st) * 512 + grp_ * 64 + lane,                     \
              &lds[buf][512 + grp_ * 64]);                                    \
    }                                                                         \
  }

  STAGE(0, 0);
  STAGE(1, 1);

  for (int st = 0; st < NST; ++st){
    if (st + 1 < NST) asm volatile("s_waitcnt vmcnt(4)" ::: "memory");
    else              asm volatile("s_waitcnt vmcnt(0)" ::: "memory");
    __builtin_amdgcn_s_barrier();
    asm volatile("" ::: "memory");
    if (st + 2 < NST) STAGE((st + 2) % 3, st + 2);

    const uint4* L = lds[st % 3];
    half8 af[4], bf[4];
#pragma unroll
    for (int mb = 0; mb < 4; ++mb) af[mb] = __builtin_bit_cast(half8, L[orow * 128 + swA[mb]]);
#pragma unroll
    for (int nb = 0; nb < 4; ++nb) bf[nb] = __builtin_bit_cast(half8, L[orow * 128 + swB[nb]]);
#pragma unroll
    for (int mb = 0; mb < 4; ++mb)
#pragma unroll
      for (int nb = 0; nb < 4; ++nb)
        acc[mb][nb] = __builtin_amdgcn_mfma_f32_16x16x32_f16(af[mb], bf[nb], acc[mb][nb], 0, 0, 0);
  }
#undef STAGE

  // epilogue: dot with W tile (W zero for j<=i masks the diagonal tiles)
  const int i0 = ti * 128 + m0, j0 = tj * 128 + n0;
  float part = 0.f;
#pragma unroll
  for (int mb = 0; mb < 4; ++mb){
#pragma unroll
    for (int r = 0; r < 4; ++r){
      const int gi = i0 + mb * 16 + orow * 4 + r;
      const float* Wr = W + (size_t)gi * FDIM + j0 + rl;
#pragma unroll
      for (int nb = 0; nb < 4; ++nb)
        part += acc[mb][nb][r] * Wr[nb * 16];
    }
  }
#pragma unroll
  for (int off = 32; off; off >>= 1) part += __shfl_xor(part, off, 64);
  if (lane == 0)
    partial[((size_t)blockIdx.y * 36 + blockIdx.x) * 4 + w] = part;
}

// ---------------------------------------------------------------------------
// final_out: reduce 4608 gram partials (redundantly per block, L2-hot),
// add 8 linear partials per row, sigmoid.
// ---------------------------------------------------------------------------
__global__ __launch_bounds__(256) void final_out(
    const float* __restrict__ partial, const float* __restrict__ linp,
    const float* __restrict__ wb, float* __restrict__ out){
  __shared__ float red[256];
  const int t = threadIdx.x;
  float s = 0.f;
#pragma unroll
  for (int k = 0; k < 18; ++k) s += partial[k * 256 + t];   // 18*256 = 4608
  red[t] = s;
  __syncthreads();
  for (int off = 128; off; off >>= 1){
    if (t < off) red[t] += red[t + off];
    __syncthreads();
  }
  const float stot = red[0] + wb[0];
  const int i = blockIdx.x * 256 + t;
  float z = stot;
#pragma unroll
  for (int p = 0; p < 8; ++p) z += linp[(size_t)p * BTOT + i];
  out[i] = 1.f / (1.f + expf(-z));
}

// ---------------------------------------------------------------------------
extern "C" void kernel_launch(void* const* d_in, const int* in_sizes, int n_in,
                              void* d_out, int out_size, void* d_ws,
                              size_t ws_size, hipStream_t stream) {
  const float* X      = (const float*)d_in[0];  // [B, F]
  const int* fields   = (const int*)d_in[1];    // [F]
  const float* ww     = (const float*)d_in[2];  // [1, F]
  const float* wbias  = (const float*)d_in[3];  // [1]
  const float* vs     = (const float*)d_in[4];  // [NF, F, E]
  float* out          = (float*)d_out;          // [B, 1]

  char* ws = (char*)d_ws;
  float* partial = (float*)ws;                        // 4608 floats (18.4 KB)
  int* grp  = (int*)(ws + (32 << 10));                // 33 ints
  int* perm = (int*)(ws + (36 << 10));                // 4 KB
  float* linp = (float*)(ws + (64 << 10));            // 8*16384 f32 = 512 KB
  float* W  = (float*)(ws + (size_t)(4 << 20));       // 4 MB at 4 MB offset
  uint4* Xbt = (uint4*)(ws + (size_t)(8 << 20));      // 32 MB at 8 MB offset

  // every cell of partial/linp/W/Xbt is written before read: no memset needed

  prep_groups<<<1, 1024, 0, stream>>>(fields, grp, perm);
  mid_fused<<<1024 + 2048, 256, 0, stream>>>(vs, grp, perm, W, X, ww, Xbt, linp);
  gram_mfma<<<dim3(36, KS), 256, 0, stream>>>(Xbt, W, partial);
  final_out<<<BTOT / 256, 256, 0, stream>>>(partial, linp, wbias, out);
}

// Round 5
// 81.089 us; speedup vs baseline: 1.5742x; 1.1529x over previous
//
#include <hip/hip_runtime.h>
#include <hip/hip_fp16.h>
#include <math.h>
#include <stdint.h>

#define FDIM 1024
#define BTOT 16384
#define EDIM 64
#define NFLD 32
#define NPANEL 4     // 4 panels of 256 cols
#define NPAIR 10     // upper-tri panel pairs
#define KS 32        // k-splits: 512 batch rows per block
#define NST 16       // stages per block: 4 k-octs (32 rows) each

typedef _Float16 half8 __attribute__((ext_vector_type(8)));
typedef float f32x4 __attribute__((ext_vector_type(4)));

__device__ __forceinline__ uint32_t pkh(float a, float b){
  _Float16 lo = (_Float16)a, hi = (_Float16)b;
  uint16_t ulo = __builtin_bit_cast(uint16_t, lo);
  uint16_t uhi = __builtin_bit_cast(uint16_t, hi);
  return ((uint32_t)uhi << 16) | (uint32_t)ulo;
}

__device__ __forceinline__ void gload16(const void* g, void* l){
  __builtin_amdgcn_global_load_lds((const __attribute__((address_space(1))) void*)g,
                                   (__attribute__((address_space(3))) void*)l,
                                   16, 0, 0);
}

// ---------------------------------------------------------------------------
// prep: bucket feature indices by field. grp[33] offsets, perm[1024] members.
// ---------------------------------------------------------------------------
__global__ void prep_groups(const int* __restrict__ fields, int* __restrict__ grp,
                            int* __restrict__ perm){
  __shared__ int cnt[NFLD];
  __shared__ int pos[NFLD];
  const int t = threadIdx.x;
  if (t < NFLD) cnt[t] = 0;
  __syncthreads();
  const int f = fields[t];
  atomicAdd(&cnt[f], 1);
  __syncthreads();
  if (t == 0){
    int s = 0;
    for (int i = 0; i < NFLD; ++i){ grp[i] = s; pos[i] = s; s += cnt[i]; }
    grp[NFLD] = s;
  }
  __syncthreads();
  const int p = atomicAdd(&pos[f], 1);
  perm[p] = t;
}

// ---------------------------------------------------------------------------
// mid_fused: blockIdx.x < 1024  -> W2 path (field-pair GEMM-let -> fp16 W)
//            blockIdx.x >= 1024 -> transpose path (X f32 -> fp16 chunk
//                                  layout, 4 panels) + linear-term partials.
// Chunk layout: Xbt[(panel*2048 + k_oct)*256 + col] = 16B of 8 consecutive
// k's of one column. No swizzle: MFMA fragment reads are 16 consecutive
// chunks per lane-group (bank-minimal), and transpose stores are contiguous.
// ---------------------------------------------------------------------------
__global__ __launch_bounds__(256) void mid_fused(
    const float* __restrict__ vs, const int* __restrict__ grp,
    const int* __restrict__ perm, _Float16* __restrict__ W,
    const float* __restrict__ X, const float* __restrict__ w,
    uint4* __restrict__ Xbt, float* __restrict__ linp){
  __shared__ float Si[64][68];
  __shared__ float Sj[64][68];
  __shared__ int gI[64], gJ[64];
  const int t = threadIdx.x;

  if (blockIdx.x >= 1024){
    // ------------------- transpose + linear path -------------------
    const int bx = blockIdx.x - 1024;      // 0..2047
    const int p  = bx & 3;                 // panel
    const int kb = bx >> 2;                // 0..511 (32-row chunk)
    const int q  = t & 63;                 // col quad within panel
    const int ro = t >> 6;                 // oct within chunk (= wave id)
    const int og = kb * 4 + ro;            // global k-oct 0..2047
    const int k0 = og * 8;
    const int c0 = p * 256 + q * 4;

    float xs[8][4];
#pragma unroll
    for (int r = 0; r < 8; ++r){
      const float4 v = *(const float4*)(X + (size_t)(k0 + r) * FDIM + c0);
      xs[r][0] = v.x; xs[r][1] = v.y; xs[r][2] = v.z; xs[r][3] = v.w;
    }

    const float4 w4 = *(const float4*)(w + c0);
#pragma unroll
    for (int r = 0; r < 8; ++r){
      float lp = xs[r][0] * w4.x + xs[r][1] * w4.y + xs[r][2] * w4.z + xs[r][3] * w4.w;
#pragma unroll
      for (int off = 32; off; off >>= 1) lp += __shfl_xor(lp, off, 64);
      if (q == 0) linp[(size_t)p * BTOT + k0 + r] = lp;
    }

    uint4* dst = Xbt + ((size_t)p * 2048 + og) * 256 + q * 4;
#pragma unroll
    for (int i = 0; i < 4; ++i){
      uint4 ch;
      ch.x = pkh(xs[0][i], xs[1][i]);
      ch.y = pkh(xs[2][i], xs[3][i]);
      ch.z = pkh(xs[4][i], xs[5][i]);
      ch.w = pkh(xs[6][i], xs[7][i]);
      dst[i] = ch;
    }
    return;
  }

  // ------------------- W2 path -------------------
  const int a = blockIdx.x >> 5, b = blockIdx.x & 31;
  const int oa = grp[a], na = grp[a + 1] - oa;
  const int ob = grp[b], nb = grp[b + 1] - ob;
  if (na == 0 || nb == 0) return;
  for (int ia0 = 0; ia0 < na; ia0 += 64){
    const int nac = min(64, na - ia0);
    for (int jb0 = 0; jb0 < nb; jb0 += 64){
      const int nbc = min(64, nb - jb0);
      __syncthreads();
      if (t < 64){
        gI[t] = (t < nac) ? perm[oa + ia0 + t] : 0;
        gJ[t] = (t < nbc) ? perm[ob + jb0 + t] : 0;
      }
      __syncthreads();
#pragma unroll
      for (int rep = 0; rep < 4; ++rep){
        const int lidx = rep * 256 + t;
        const int r = lidx >> 4, e4 = (lidx & 15) * 4;
        if (r < nac)
          *(float4*)&Si[r][e4] = *(const float4*)(vs + ((size_t)b * FDIM + gI[r]) * EDIM + e4);
        if (r < nbc)
          *(float4*)&Sj[r][e4] = *(const float4*)(vs + ((size_t)a * FDIM + gJ[r]) * EDIM + e4);
      }
      __syncthreads();
      const int jr = t & 63;
      for (int ko = 0; ko * 4 < nac; ++ko){
        const int ir = ko * 4 + (t >> 6);
        if (ir < nac && jr < nbc){
          float dot = 0.f;
#pragma unroll
          for (int e4 = 0; e4 < EDIM; e4 += 4){
            const float4 x = *(const float4*)&Si[ir][e4];
            const float4 y = *(const float4*)&Sj[jr][e4];
            dot += x.x * y.x + x.y * y.y + x.z * y.z + x.w * y.w;
          }
          const int gi = gI[ir], gj = gJ[jr];
          W[(size_t)gi * FDIM + gj] = (gj > gi) ? (_Float16)dot : (_Float16)0.f;
        }
      }
    }
  }
}

// ---------------------------------------------------------------------------
// gram256: 256x256 upper-tri panel pairs (10) x KS k-splits, 8 waves.
// Depth-2 counted-vmcnt pipeline: 3 LDS buffers (32 KB each), per stage
//   s_waitcnt vmcnt(4) -> s_barrier -> issue STAGE(t+2) -> ds_read+MFMA(t).
// Per wave per stage: 4 gload16 (vmcnt counts 4/stage/wave), 12 ds_read_b128,
// 32 MFMA. Wave (wr,wc) owns a 128x64 sub-tile: acc[8][4] f32x4.
// Epilogue dots acc with fp16 W tile, wave-reduces, writes per-wave partial.
// ---------------------------------------------------------------------------
__global__ __launch_bounds__(512, 2) void gram256(
    const uint4* __restrict__ Xbt, const _Float16* __restrict__ W,
    float* __restrict__ partial){
  int pp = blockIdx.x, ti = 0, rem = NPANEL;
  while (pp >= rem){ pp -= rem; ++ti; --rem; }
  const int tj = ti + pp;
  const int ko0 = blockIdx.y * (2048 / KS);   // 64 octs = 512 rows per block

  __shared__ uint4 lds[3][2048];   // per buf 32KB: [oct(4)][A 256 | B 256]
  const int t = threadIdx.x, w = t >> 6, lane = t & 63;
  const int wr = w >> 2, wc = w & 3;          // wave sub-tile (2 x 4)
  const int orow = lane >> 4, rl = lane & 15;

  const uint4* gA = Xbt + ((size_t)ti * 2048 + ko0) * 256;
  const uint4* gB = Xbt + ((size_t)tj * 2048 + ko0) * 256;

  f32x4 acc[8][4];
#pragma unroll
  for (int i = 0; i < 8; ++i)
#pragma unroll
    for (int j = 0; j < 4; ++j) acc[i][j] = {0.f, 0.f, 0.f, 0.f};

  // stage st (4 octs = 32 rows): 2048 chunks; 4 gload16 per wave.
#define STAGE(buf, st)                                                        \
  {                                                                           \
    _Pragma("unroll")                                                         \
    for (int n = 0; n < 4; ++n){                                              \
      const int g = w * 4 + n;                                                \
      const int oct = g >> 3, side = (g >> 2) & 1, cg = g & 3;                \
      const uint4* src = (side ? gB : gA) +                                   \
          (size_t)((st) * 4 + oct) * 256 + cg * 64 + lane;                    \
      gload16(src, &lds[buf][oct * 512 + side * 256 + cg * 64]);              \
    }                                                                         \
  }

  STAGE(0, 0);
  STAGE(1, 1);

  for (int st = 0; st < NST; ++st){
    if (st + 1 < NST) asm volatile("s_waitcnt vmcnt(4)" ::: "memory");
    else              asm volatile("s_waitcnt vmcnt(0)" ::: "memory");
    __builtin_amdgcn_s_barrier();
    asm volatile("" ::: "memory");
    if (st + 2 < NST) STAGE((st + 2) % 3, st + 2);

    const uint4* L = lds[st % 3];
    const int ob = orow * 512;
    half8 af[8], bf[4];
#pragma unroll
    for (int nb = 0; nb < 4; ++nb)
      bf[nb] = __builtin_bit_cast(half8, L[ob + 256 + wc * 64 + nb * 16 + rl]);
#pragma unroll
    for (int mb = 0; mb < 8; ++mb)
      af[mb] = __builtin_bit_cast(half8, L[ob + wr * 128 + mb * 16 + rl]);
#pragma unroll
    for (int mb = 0; mb < 8; ++mb)
#pragma unroll
      for (int nb = 0; nb < 4; ++nb)
        acc[mb][nb] = __builtin_amdgcn_mfma_f32_16x16x32_f16(af[mb], bf[nb], acc[mb][nb], 0, 0, 0);
  }
#undef STAGE

  // epilogue: dot with fp16 W tile (W zero for j<=i masks diagonal pairs)
  const _Float16* Wt = W + ((size_t)(ti * 256 + wr * 128)) * FDIM
                         + tj * 256 + wc * 64;
  float part = 0.f;
#pragma unroll
  for (int mb = 0; mb < 8; ++mb){
#pragma unroll
    for (int r = 0; r < 4; ++r){
      const _Float16* Wr = Wt + (size_t)(mb * 16 + orow * 4 + r) * FDIM + rl;
#pragma unroll
      for (int nb = 0; nb < 4; ++nb)
        part += acc[mb][nb][r] * (float)Wr[nb * 16];
    }
  }
#pragma unroll
  for (int off = 32; off; off >>= 1) part += __shfl_xor(part, off, 64);
  if (lane == 0)
    partial[((size_t)blockIdx.y * NPAIR + blockIdx.x) * 8 + w] = part;
}

// ---------------------------------------------------------------------------
// final_out: reduce 2560 gram partials (redundantly per block, L2-hot),
// add 4 linear partials per row, sigmoid.
// ---------------------------------------------------------------------------
__global__ __launch_bounds__(256) void final_out(
    const float* __restrict__ partial, const float* __restrict__ linp,
    const float* __restrict__ wb, float* __restrict__ out){
  __shared__ float red[256];
  const int t = threadIdx.x;
  float s = 0.f;
#pragma unroll
  for (int k = 0; k < 10; ++k) s += partial[k * 256 + t];   // 10*256 = 2560
  red[t] = s;
  __syncthreads();
  for (int off = 128; off; off >>= 1){
    if (t < off) red[t] += red[t + off];
    __syncthreads();
  }
  const float stot = red[0] + wb[0];
  const int i = blockIdx.x * 256 + t;
  float z = stot;
#pragma unroll
  for (int p = 0; p < NPANEL; ++p) z += linp[(size_t)p * BTOT + i];
  out[i] = 1.f / (1.f + expf(-z));
}

// ---------------------------------------------------------------------------
extern "C" void kernel_launch(void* const* d_in, const int* in_sizes, int n_in,
                              void* d_out, int out_size, void* d_ws,
                              size_t ws_size, hipStream_t stream) {
  const float* X      = (const float*)d_in[0];  // [B, F]
  const int* fields   = (const int*)d_in[1];    // [F]
  const float* ww     = (const float*)d_in[2];  // [1, F]
  const float* wbias  = (const float*)d_in[3];  // [1]
  const float* vs     = (const float*)d_in[4];  // [NF, F, E]
  float* out          = (float*)d_out;          // [B, 1]

  char* ws = (char*)d_ws;
  float* partial = (float*)ws;                        // 2560 floats
  int* grp  = (int*)(ws + (32 << 10));                // 33 ints
  int* perm = (int*)(ws + (36 << 10));                // 4 KB
  float* linp = (float*)(ws + (64 << 10));            // 4*16384 f32 = 256 KB
  _Float16* W = (_Float16*)(ws + (size_t)(4 << 20));  // 2 MB fp16 at 4 MB
  uint4* Xbt = (uint4*)(ws + (size_t)(8 << 20));      // 32 MB at 8 MB offset

  // every cell of partial/linp/W/Xbt is written before read: no memset needed

  prep_groups<<<1, 1024, 0, stream>>>(fields, grp, perm);
  mid_fused<<<1024 + 2048, 256, 0, stream>>>(vs, grp, perm, W, X, ww, Xbt, linp);
  gram256<<<dim3(NPAIR, KS), 512, 0, stream>>>(Xbt, W, partial);
  final_out<<<BTOT / 256, 256, 0, stream>>>(partial, linp, wbias, out);
}

// Round 6
// 77.446 us; speedup vs baseline: 1.6482x; 1.0470x over previous
//
#include <hip/hip_runtime.h>
#include <hip/hip_fp16.h>
#include <math.h>
#include <stdint.h>

#define FDIM 1024
#define BTOT 16384
#define EDIM 64
#define NFLD 32
#define NPANEL 4            // 4 panels of 256 cols
#define NPAIRS 10           // upper-tri panel pairs
#define TOTSTAGE (NPAIRS * 512)  // 5120 32-row stages over all pairs
#define NBLK 512            // gram blocks (2/CU capacity, perfectly balanced)
#define SPB (TOTSTAGE / NBLK)    // 10 stages per block

typedef _Float16 half8 __attribute__((ext_vector_type(8)));
typedef float f32x4 __attribute__((ext_vector_type(4)));

__device__ __forceinline__ uint32_t pkh(float a, float b){
  _Float16 lo = (_Float16)a, hi = (_Float16)b;
  uint16_t ulo = __builtin_bit_cast(uint16_t, lo);
  uint16_t uhi = __builtin_bit_cast(uint16_t, hi);
  return ((uint32_t)uhi << 16) | (uint32_t)ulo;
}

__device__ __forceinline__ void gload16(const void* g, void* l){
  __builtin_amdgcn_global_load_lds((const __attribute__((address_space(1))) void*)g,
                                   (__attribute__((address_space(3))) void*)l,
                                   16, 0, 0);
}

__device__ __forceinline__ void decode_pair(int p, int& ti, int& tj){
  int rem = NPANEL, t0 = 0;
  while (p >= rem){ p -= rem; ++t0; --rem; }
  ti = t0; tj = t0 + p;
}

__device__ __forceinline__ float fget(const float4& v, int i){
  switch (i){ case 0: return v.x; case 1: return v.y; case 2: return v.z; default: return v.w; }
}

// ---------------------------------------------------------------------------
// prep: bucket feature indices by field. grp[33] offsets, perm[1024] members.
// ---------------------------------------------------------------------------
__global__ void prep_groups(const int* __restrict__ fields, int* __restrict__ grp,
                            int* __restrict__ perm){
  __shared__ int cnt[NFLD];
  __shared__ int pos[NFLD];
  const int t = threadIdx.x;
  if (t < NFLD) cnt[t] = 0;
  __syncthreads();
  const int f = fields[t];
  atomicAdd(&cnt[f], 1);
  __syncthreads();
  if (t == 0){
    int s = 0;
    for (int i = 0; i < NFLD; ++i){ grp[i] = s; pos[i] = s; s += cnt[i]; }
    grp[NFLD] = s;
  }
  __syncthreads();
  const int p = atomicAdd(&pos[f], 1);
  perm[p] = t;
}

// ---------------------------------------------------------------------------
// mid_fused: blockIdx.x < 1024  -> W2 path (field-pair GEMM-let -> fp16 W)
//            blockIdx.x >= 1024 -> transpose path (X f32 -> fp16 chunk
//                                  layout) + linear-term partials.
// Transpose stores are now coalesced: pack chunks into a per-wave LDS tile,
// then consecutive lanes store consecutive uint4 (1 KB contiguous / instr).
// ---------------------------------------------------------------------------
__global__ __launch_bounds__(256) void mid_fused(
    const float* __restrict__ vs, const int* __restrict__ grp,
    const int* __restrict__ perm, _Float16* __restrict__ W,
    const float* __restrict__ X, const float* __restrict__ w,
    uint4* __restrict__ Xbt, float* __restrict__ linp){
  const int t = threadIdx.x;

  if (blockIdx.x >= 1024){
    // ------------------- transpose + linear path -------------------
    __shared__ uint4 tb[4][256];
    const int bx = blockIdx.x - 1024;      // 0..2047
    const int p  = bx & 3;                 // panel
    const int kb = bx >> 2;                // 0..511 (32-row chunk)
    const int ro = t >> 6;                 // wave = oct within chunk
    const int l  = t & 63;
    const int og = kb * 4 + ro;            // global k-oct
    const int k0 = og * 8;
    const int c0 = p * 256;

    float4 rv[8];
#pragma unroll
    for (int r = 0; r < 8; ++r)
      rv[r] = *(const float4*)(X + (size_t)(k0 + r) * FDIM + c0 + l * 4);

    const float4 w4 = *(const float4*)(w + c0 + l * 4);
#pragma unroll
    for (int r = 0; r < 8; ++r){
      float lp = rv[r].x * w4.x + rv[r].y * w4.y + rv[r].z * w4.z + rv[r].w * w4.w;
#pragma unroll
      for (int off = 32; off; off >>= 1) lp += __shfl_xor(lp, off, 64);
      if (l == 0) linp[(size_t)p * BTOT + k0 + r] = lp;
    }

#pragma unroll
    for (int i = 0; i < 4; ++i){
      uint4 ch;
      ch.x = pkh(fget(rv[0], i), fget(rv[1], i));
      ch.y = pkh(fget(rv[2], i), fget(rv[3], i));
      ch.z = pkh(fget(rv[4], i), fget(rv[5], i));
      ch.w = pkh(fget(rv[6], i), fget(rv[7], i));
      tb[ro][l * 4 + i] = ch;             // chunk for col l*4+i
    }
    __syncthreads();
    uint4* dst = Xbt + ((size_t)p * 2048 + og) * 256;
#pragma unroll
    for (int i = 0; i < 4; ++i)
      dst[l + 64 * i] = tb[ro][l + 64 * i];  // coalesced 1KB stores
    return;
  }

  // ------------------- W2 path -------------------
  __shared__ float Si[64][68];
  __shared__ float Sj[64][68];
  __shared__ int gI[64], gJ[64];
  const int a = blockIdx.x >> 5, b = blockIdx.x & 31;
  const int oa = grp[a], na = grp[a + 1] - oa;
  const int ob = grp[b], nb = grp[b + 1] - ob;
  if (na == 0 || nb == 0) return;
  for (int ia0 = 0; ia0 < na; ia0 += 64){
    const int nac = min(64, na - ia0);
    for (int jb0 = 0; jb0 < nb; jb0 += 64){
      const int nbc = min(64, nb - jb0);
      __syncthreads();
      if (t < 64){
        gI[t] = (t < nac) ? perm[oa + ia0 + t] : 0;
        gJ[t] = (t < nbc) ? perm[ob + jb0 + t] : 0;
      }
      __syncthreads();
#pragma unroll
      for (int rep = 0; rep < 4; ++rep){
        const int lidx = rep * 256 + t;
        const int r = lidx >> 4, e4 = (lidx & 15) * 4;
        if (r < nac)
          *(float4*)&Si[r][e4] = *(const float4*)(vs + ((size_t)b * FDIM + gI[r]) * EDIM + e4);
        if (r < nbc)
          *(float4*)&Sj[r][e4] = *(const float4*)(vs + ((size_t)a * FDIM + gJ[r]) * EDIM + e4);
      }
      __syncthreads();
      const int jr = t & 63;
      for (int ko = 0; ko * 4 < nac; ++ko){
        const int ir = ko * 4 + (t >> 6);
        if (ir < nac && jr < nbc){
          float dot = 0.f;
#pragma unroll
          for (int e4 = 0; e4 < EDIM; e4 += 4){
            const float4 x = *(const float4*)&Si[ir][e4];
            const float4 y = *(const float4*)&Sj[jr][e4];
            dot += x.x * y.x + x.y * y.y + x.z * y.z + x.w * y.w;
          }
          const int gi = gI[ir], gj = gJ[jr];
          W[(size_t)gi * FDIM + gj] = (gj > gi) ? (_Float16)dot : (_Float16)0.f;
        }
      }
    }
  }
}

// ---------------------------------------------------------------------------
// gram256: flattened perfectly-balanced grid. Global stage s in [0,5120):
// pair = s>>9, k-range = (s&511)*32 rows. 512 blocks x 10 stages each.
// Depth-3 counted-vmcnt pipeline: 4 LDS buffers (32 KB each); steady-state
// wait vmcnt(8) (2 stages in flight past the waited one). Blocks spanning a
// pair boundary (9/512) flush acc mid-loop to a second partial slot; every
// block writes both slots (unused slot zeroed - poison-safe).
// ---------------------------------------------------------------------------
__global__ __launch_bounds__(512, 2) void gram256(
    const uint4* __restrict__ Xbt, const _Float16* __restrict__ W,
    float* __restrict__ partial){
  const int b = blockIdx.x;
  const int gs0 = b * SPB;
  __shared__ uint4 lds[4][2048];   // 4 bufs x 32KB: [oct(4)][A 256 | B 256]
  const int t = threadIdx.x, w = t >> 6, lane = t & 63;
  const int wr = w >> 2, wc = w & 3;          // wave sub-tile (2 x 4)
  const int orow = lane >> 4, rl = lane & 15;

  f32x4 acc[8][4];
#pragma unroll
  for (int i = 0; i < 8; ++i)
#pragma unroll
    for (int j = 0; j < 4; ++j) acc[i][j] = {0.f, 0.f, 0.f, 0.f};

  auto stage = [&](int buf, int s){
    int ti, tj; decode_pair(s >> 9, ti, tj);
    const int ks = s & 511;
#pragma unroll
    for (int n = 0; n < 4; ++n){
      const int g = w * 4 + n;
      const int oct = g >> 3, side = (g >> 2) & 1, cg = g & 3;
      const int panel = side ? tj : ti;
      const uint4* src = Xbt + ((size_t)panel * 2048 + ks * 4 + oct) * 256
                             + cg * 64 + lane;
      gload16(src, &lds[buf][oct * 512 + side * 256 + cg * 64]);
    }
  };

  auto epilogue = [&](int p, int slot){
    int ti, tj; decode_pair(p, ti, tj);
    const _Float16* Wt = W + (size_t)(ti * 256 + wr * 128) * FDIM
                           + tj * 256 + wc * 64;
    float part = 0.f;
#pragma unroll
    for (int mb = 0; mb < 8; ++mb)
#pragma unroll
      for (int r = 0; r < 4; ++r){
        const _Float16* Wr = Wt + (size_t)(mb * 16 + orow * 4 + r) * FDIM + rl;
#pragma unroll
        for (int nb = 0; nb < 4; ++nb)
          part += acc[mb][nb][r] * (float)Wr[nb * 16];
      }
#pragma unroll
    for (int off = 32; off; off >>= 1) part += __shfl_xor(part, off, 64);
    if (lane == 0) partial[((size_t)b * 2 + slot) * 8 + w] = part;
  };

  stage(0, gs0); stage(1, gs0 + 1); stage(2, gs0 + 2);

  int curP = gs0 >> 9;
  int seg = 0;
#pragma unroll 1
  for (int st = 0; st < SPB; ++st){
    // wait for stage st's 4 loads; keep later prefetches in flight
    if (st < SPB - 2)       asm volatile("s_waitcnt vmcnt(8)" ::: "memory");
    else if (st == SPB - 2) asm volatile("s_waitcnt vmcnt(4)" ::: "memory");
    else                    asm volatile("s_waitcnt vmcnt(0)" ::: "memory");
    __builtin_amdgcn_s_barrier();
    asm volatile("" ::: "memory");
    if (st + 3 < SPB) stage((st + 3) & 3, gs0 + st + 3);

    const int p = (gs0 + st) >> 9;
    if (p != curP){                 // pair boundary (block-uniform, rare)
      epilogue(curP, 0);
#pragma unroll
      for (int i = 0; i < 8; ++i)
#pragma unroll
        for (int j = 0; j < 4; ++j) acc[i][j] = {0.f, 0.f, 0.f, 0.f};
      curP = p; seg = 1;
    }

    const uint4* L = lds[st & 3];
    const int ob = orow * 512;
    half8 af[8], bf[4];
#pragma unroll
    for (int nb = 0; nb < 4; ++nb)
      bf[nb] = __builtin_bit_cast(half8, L[ob + 256 + wc * 64 + nb * 16 + rl]);
#pragma unroll
    for (int mb = 0; mb < 8; ++mb)
      af[mb] = __builtin_bit_cast(half8, L[ob + wr * 128 + mb * 16 + rl]);
#pragma unroll
    for (int mb = 0; mb < 8; ++mb)
#pragma unroll
      for (int nb = 0; nb < 4; ++nb)
        acc[mb][nb] = __builtin_amdgcn_mfma_f32_16x16x32_f16(af[mb], bf[nb], acc[mb][nb], 0, 0, 0);
  }

  epilogue(curP, seg);
  if (seg == 0 && lane == 0)
    partial[((size_t)b * 2 + 1) * 8 + w] = 0.f;   // poison-safe unused slot
}

// ---------------------------------------------------------------------------
// final_out: reduce 8192 gram partial slots (redundantly per block, L2-hot),
// add 4 linear partials per row, sigmoid.
// ---------------------------------------------------------------------------
__global__ __launch_bounds__(256) void final_out(
    const float* __restrict__ partial, const float* __restrict__ linp,
    const float* __restrict__ wb, float* __restrict__ out){
  __shared__ float red[256];
  const int t = threadIdx.x;
  float s = 0.f;
#pragma unroll
  for (int k = 0; k < 32; ++k) s += partial[k * 256 + t];   // 32*256 = 8192
  red[t] = s;
  __syncthreads();
  for (int off = 128; off; off >>= 1){
    if (t < off) red[t] += red[t + off];
    __syncthreads();
  }
  const float stot = red[0] + wb[0];
  const int i = blockIdx.x * 256 + t;
  float z = stot;
#pragma unroll
  for (int p = 0; p < NPANEL; ++p) z += linp[(size_t)p * BTOT + i];
  out[i] = 1.f / (1.f + expf(-z));
}

// ---------------------------------------------------------------------------
extern "C" void kernel_launch(void* const* d_in, const int* in_sizes, int n_in,
                              void* d_out, int out_size, void* d_ws,
                              size_t ws_size, hipStream_t stream) {
  const float* X      = (const float*)d_in[0];  // [B, F]
  const int* fields   = (const int*)d_in[1];    // [F]
  const float* ww     = (const float*)d_in[2];  // [1, F]
  const float* wbias  = (const float*)d_in[3];  // [1]
  const float* vs     = (const float*)d_in[4];  // [NF, F, E]
  float* out          = (float*)d_out;          // [B, 1]

  char* ws = (char*)d_ws;
  float* partial = (float*)ws;                        // 8192 floats = 32 KB
  int* grp  = (int*)(ws + (33 << 10));                // 33 ints
  int* perm = (int*)(ws + (36 << 10));                // 4 KB
  float* linp = (float*)(ws + (64 << 10));            // 4*16384 f32 = 256 KB
  _Float16* W = (_Float16*)(ws + (size_t)(4 << 20));  // 2 MB fp16 at 4 MB
  uint4* Xbt = (uint4*)(ws + (size_t)(8 << 20));      // 32 MB at 8 MB offset

  // every cell of partial/linp/W/Xbt is written before read: no memset needed

  prep_groups<<<1, 1024, 0, stream>>>(fields, grp, perm);
  mid_fused<<<1024 + 2048, 256, 0, stream>>>(vs, grp, perm, W, X, ww, Xbt, linp);
  gram256<<<NBLK, 512, 0, stream>>>(Xbt, W, partial);
  final_out<<<BTOT / 256, 256, 0, stream>>>(partial, linp, wbias, out);
}

// Round 7
// 70.075 us; speedup vs baseline: 1.8216x; 1.1052x over previous
//
#include <hip/hip_runtime.h>
#include <hip/hip_fp16.h>
#include <math.h>
#include <stdint.h>

#define FDIM 1024
#define BTOT 16384
#define EDIM 64
#define NFLD 32
#define NPANEL 4            // 4 panels of 256 cols
#define NPAIRS 10           // upper-tri panel pairs

typedef _Float16 half8 __attribute__((ext_vector_type(8)));
typedef float f32x4 __attribute__((ext_vector_type(4)));

__device__ __forceinline__ uint32_t pkh(float a, float b){
  _Float16 lo = (_Float16)a, hi = (_Float16)b;
  uint16_t ulo = __builtin_bit_cast(uint16_t, lo);
  uint16_t uhi = __builtin_bit_cast(uint16_t, hi);
  return ((uint32_t)uhi << 16) | (uint32_t)ulo;
}

__device__ __forceinline__ void gload16(const void* g, void* l){
  __builtin_amdgcn_global_load_lds((const __attribute__((address_space(1))) void*)g,
                                   (__attribute__((address_space(3))) void*)l,
                                   16, 0, 0);
}

__device__ __forceinline__ float fget(const float4& v, int i){
  switch (i){ case 0: return v.x; case 1: return v.y; case 2: return v.z; default: return v.w; }
}

// pair index for ti<=tj: (0,0)=0 (0,1)=1 (0,2)=2 (0,3)=3 (1,1)=4 ... (3,3)=9
__device__ __forceinline__ int pairId(int ti, int tj){
  return ti * NPANEL - (ti * (ti + 1)) / 2 + tj;
}

// ---------------------------------------------------------------------------
// mid_fused: blockIdx.x < 1024  -> W2 path: in-block field bucketing (prep
//            merged), field-pair GEMM-lets, store into the gram-ready fp16
//            Wp layout: Wp[(P*8+w)*8192 + ((mb*2+h)*64+lane)*8 + r2*4+nb]
//            for element (i,j): P=pair(panel_i,panel_j), w=wave subtile,
//            lane/mb/h/r2/nb from the MFMA C-fragment mapping. Strict-upper
//            masking baked in (0 for j<=i). Every pi<=pj cell written once.
//            blockIdx.x >= 1024 -> transpose path (X f32 -> fp16 chunk
//            layout, coalesced via LDS bounce) + linear-term partials.
// ---------------------------------------------------------------------------
__global__ __launch_bounds__(256) void mid_fused(
    const float* __restrict__ vs, const int* __restrict__ fields,
    _Float16* __restrict__ Wp,
    const float* __restrict__ X, const float* __restrict__ w,
    uint4* __restrict__ Xbt, float* __restrict__ linp){
  const int t = threadIdx.x;

  if (blockIdx.x >= 1024){
    // ------------------- transpose + linear path -------------------
    __shared__ uint4 tb[4][256];
    const int bx = blockIdx.x - 1024;      // 0..2047
    const int p  = bx & 3;                 // panel
    const int kb = bx >> 2;                // 0..511 (32-row chunk)
    const int ro = t >> 6;                 // wave = oct within chunk
    const int l  = t & 63;
    const int og = kb * 4 + ro;            // global k-oct
    const int k0 = og * 8;
    const int c0 = p * 256;

    float4 rv[8];
#pragma unroll
    for (int r = 0; r < 8; ++r)
      rv[r] = *(const float4*)(X + (size_t)(k0 + r) * FDIM + c0 + l * 4);

    const float4 w4 = *(const float4*)(w + c0 + l * 4);
#pragma unroll
    for (int r = 0; r < 8; ++r){
      float lp = rv[r].x * w4.x + rv[r].y * w4.y + rv[r].z * w4.z + rv[r].w * w4.w;
#pragma unroll
      for (int off = 32; off; off >>= 1) lp += __shfl_xor(lp, off, 64);
      if (l == 0) linp[(size_t)p * BTOT + k0 + r] = lp;
    }

#pragma unroll
    for (int i = 0; i < 4; ++i){
      uint4 ch;
      ch.x = pkh(fget(rv[0], i), fget(rv[1], i));
      ch.y = pkh(fget(rv[2], i), fget(rv[3], i));
      ch.z = pkh(fget(rv[4], i), fget(rv[5], i));
      ch.w = pkh(fget(rv[6], i), fget(rv[7], i));
      tb[ro][l * 4 + i] = ch;             // chunk for col l*4+i
    }
    __syncthreads();
    uint4* dst = Xbt + ((size_t)p * 2048 + og) * 256;
#pragma unroll
    for (int i = 0; i < 4; ++i)
      dst[l + 64 * i] = tb[ro][l + 64 * i];  // coalesced 1KB stores
    return;
  }

  // ------------------- W2 path (with merged prep) -------------------
  __shared__ float Si[64][68];
  __shared__ float Sj[64][68];
  __shared__ int gI[64], gJ[64];
  __shared__ int cnt[NFLD], pos[NFLD], off[NFLD + 1];
  __shared__ int permS[FDIM];

  if (t < NFLD) cnt[t] = 0;
  __syncthreads();
#pragma unroll
  for (int r = 0; r < 4; ++r) atomicAdd(&cnt[fields[t + 256 * r]], 1);
  __syncthreads();
  if (t == 0){
    int s = 0;
    for (int i = 0; i < NFLD; ++i){ off[i] = s; s += cnt[i]; }
    off[NFLD] = s;
  }
  __syncthreads();
  if (t < NFLD) pos[t] = off[t];
  __syncthreads();
#pragma unroll
  for (int r = 0; r < 4; ++r){
    const int idx = t + 256 * r;
    const int p = atomicAdd(&pos[fields[idx]], 1);
    permS[p] = idx;
  }
  __syncthreads();

  const int a = blockIdx.x >> 5, b = blockIdx.x & 31;
  const int oa = off[a], na = off[a + 1] - oa;
  const int ob = off[b], nb_ = off[b + 1] - ob;
  if (na == 0 || nb_ == 0) return;
  for (int ia0 = 0; ia0 < na; ia0 += 64){
    const int nac = min(64, na - ia0);
    for (int jb0 = 0; jb0 < nb_; jb0 += 64){
      const int nbc = min(64, nb_ - jb0);
      __syncthreads();
      if (t < 64){
        gI[t] = (t < nac) ? permS[oa + ia0 + t] : 0;
        gJ[t] = (t < nbc) ? permS[ob + jb0 + t] : 0;
      }
      __syncthreads();
#pragma unroll
      for (int rep = 0; rep < 4; ++rep){
        const int lidx = rep * 256 + t;
        const int r = lidx >> 4, e4 = (lidx & 15) * 4;
        if (r < nac)
          *(float4*)&Si[r][e4] = *(const float4*)(vs + ((size_t)b * FDIM + gI[r]) * EDIM + e4);
        if (r < nbc)
          *(float4*)&Sj[r][e4] = *(const float4*)(vs + ((size_t)a * FDIM + gJ[r]) * EDIM + e4);
      }
      __syncthreads();
      const int jr = t & 63;
      for (int ko = 0; ko * 4 < nac; ++ko){
        const int ir = ko * 4 + (t >> 6);
        if (ir < nac && jr < nbc){
          float dot = 0.f;
#pragma unroll
          for (int e4 = 0; e4 < EDIM; e4 += 4){
            const float4 x = *(const float4*)&Si[ir][e4];
            const float4 y = *(const float4*)&Sj[jr][e4];
            dot += x.x * y.x + x.y * y.y + x.z * y.z + x.w * y.w;
          }
          const int gi = gI[ir], gj = gJ[jr];
          const int pi = gi >> 8, pj = gj >> 8;
          if (pi <= pj){
            const float v = (gj > gi) ? dot : 0.f;
            const int li = gi & 255, lj = gj & 255;
            const int P  = pairId(pi, pj);
            const int w8 = (li >> 7) * 4 + (lj >> 6);
            const int mb = (li >> 4) & 7, r_ = li & 3;
            const int lane = ((li >> 2) & 3) * 16 + (lj & 15);
            const int nbv = (lj >> 4) & 3;
            const size_t o_ = (size_t)(P * 8 + w8) * 8192
                            + (size_t)((mb * 2 + (r_ >> 1)) * 64 + lane) * 8
                            + (r_ & 1) * 4 + nbv;
            Wp[o_] = (_Float16)v;
          }
        }
      }
    }
  }
}

// ---------------------------------------------------------------------------
// gram_kc: 256 blocks (1/CU), each owns ONE 64-row k-chunk. Stages the full
// 4-panel fp16 slice (128 KB LDS, 16 gload16/thread, panel-major issue) and
// computes all 10 panel-pairs from LDS, dotting each P-chunk with Wp
// immediately (sum over k-chunks distributes). Xbt is read EXACTLY ONCE
// (32 MB total). Pair groups gated by counted vmcnt (12/8/4/0) + s_barrier:
// pair (0,0) starts after only panel 0 has landed. Per-wave running W-dot
// partial, block-reduced at the end. No same-address atomics.
// ---------------------------------------------------------------------------
__global__ __launch_bounds__(512, 2) void gram_kc(
    const uint4* __restrict__ Xbt, const _Float16* __restrict__ Wp,
    float* __restrict__ partial){
  __shared__ uint4 lds4[8192];   // [oct(8)][panel(4)][col(256)] = 128 KB
  const int t = threadIdx.x, w = t >> 6, lane = t & 63;
  const int orow = lane >> 4, rl = lane & 15;
  const int wr = w >> 2, wc = w & 3;     // wave sub-tile (2 x 4) of 256x256
  const int b8 = blockIdx.x * 8;         // first k-oct of this chunk

  // issue all staging, panel-major (4 loads per thread per panel)
#pragma unroll
  for (int p = 0; p < NPANEL; ++p)
#pragma unroll
    for (int q = 0; q < 4; ++q){
      const int m = q * 512 + t;
      const int o = m >> 8, c = m & 255;
      gload16(Xbt + ((size_t)p * 2048 + b8 + o) * 256 + c,
              lds4 + o * 1024 + p * 256 + c);
    }

  float wsum = 0.f;

  auto loadB = [&](int tj, half8 (&bf)[2][4]){
#pragma unroll
    for (int s = 0; s < 2; ++s)
#pragma unroll
      for (int nb = 0; nb < 4; ++nb)
        bf[s][nb] = __builtin_bit_cast(half8,
            lds4[(s * 4 + orow) * 1024 + tj * 256 + wc * 64 + nb * 16 + rl]);
  };

  auto body = [&](int ti, int tj, const half8 (&bf)[2][4]){
    f32x4 acc[8][4];
#pragma unroll
    for (int i = 0; i < 8; ++i)
#pragma unroll
      for (int j = 0; j < 4; ++j) acc[i][j] = {0.f, 0.f, 0.f, 0.f};
#pragma unroll
    for (int s = 0; s < 2; ++s)
#pragma unroll
      for (int mb = 0; mb < 8; ++mb){
        const half8 af = __builtin_bit_cast(half8,
            lds4[(s * 4 + orow) * 1024 + ti * 256 + wr * 128 + mb * 16 + rl]);
#pragma unroll
        for (int nb = 0; nb < 4; ++nb)
          acc[mb][nb] = __builtin_amdgcn_mfma_f32_16x16x32_f16(
              af, bf[s][nb], acc[mb][nb], 0, 0, 0);
      }
    // W-dot epilogue: 16 coalesced b128 loads from the pair/wave Wp subtile
    const uint4* wp = (const uint4*)(Wp + (size_t)(pairId(ti, tj) * 8 + w) * 8192);
#pragma unroll
    for (int mb = 0; mb < 8; ++mb)
#pragma unroll
      for (int h = 0; h < 2; ++h){
        const half8 hv = __builtin_bit_cast(half8, wp[(mb * 2 + h) * 64 + lane]);
#pragma unroll
        for (int r2 = 0; r2 < 2; ++r2)
#pragma unroll
          for (int nb = 0; nb < 4; ++nb)
            wsum += (float)hv[r2 * 4 + nb] * acc[mb][nb][2 * h + r2];
      }
  };

#define GRAM_GROUP(G, VM)                                         \
  asm volatile("s_waitcnt vmcnt(" #VM ")" ::: "memory");          \
  __builtin_amdgcn_s_barrier();                                   \
  {                                                               \
    half8 bf[2][4];                                               \
    loadB(G, bf);                                                 \
    _Pragma("unroll 1")                                           \
    for (int ti = 0; ti <= (G); ++ti) body(ti, (G), bf);          \
  }

  GRAM_GROUP(0, 12)
  GRAM_GROUP(1, 8)
  GRAM_GROUP(2, 4)
  GRAM_GROUP(3, 0)
#undef GRAM_GROUP

  // block reduce: wave-reduce, then cross-wave via LDS (reuse, post-barrier)
#pragma unroll
  for (int off = 32; off; off >>= 1) wsum += __shfl_xor(wsum, off, 64);
  __syncthreads();
  float* red = (float*)lds4;
  if (lane == 0) red[w] = wsum;
  __syncthreads();
  if (t == 0){
    float s = 0.f;
#pragma unroll
    for (int i = 0; i < 8; ++i) s += red[i];
    partial[blockIdx.x] = s;
  }
}

// ---------------------------------------------------------------------------
// final_out: reduce 256 per-block gram partials (redundantly per block,
// L2-hot), add 4 linear partials per row, sigmoid.
// ---------------------------------------------------------------------------
__global__ __launch_bounds__(256) void final_out(
    const float* __restrict__ partial, const float* __restrict__ linp,
    const float* __restrict__ wb, float* __restrict__ out){
  __shared__ float red[256];
  const int t = threadIdx.x;
  red[t] = partial[t];
  __syncthreads();
  for (int off = 128; off; off >>= 1){
    if (t < off) red[t] += red[t + off];
    __syncthreads();
  }
  const float stot = red[0] + wb[0];
  const int i = blockIdx.x * 256 + t;
  float z = stot;
#pragma unroll
  for (int p = 0; p < NPANEL; ++p) z += linp[(size_t)p * BTOT + i];
  out[i] = 1.f / (1.f + expf(-z));
}

// ---------------------------------------------------------------------------
extern "C" void kernel_launch(void* const* d_in, const int* in_sizes, int n_in,
                              void* d_out, int out_size, void* d_ws,
                              size_t ws_size, hipStream_t stream) {
  const float* X      = (const float*)d_in[0];  // [B, F]
  const int* fields   = (const int*)d_in[1];    // [F]
  const float* ww     = (const float*)d_in[2];  // [1, F]
  const float* wbias  = (const float*)d_in[3];  // [1]
  const float* vs     = (const float*)d_in[4];  // [NF, F, E]
  float* out          = (float*)d_out;          // [B, 1]

  char* ws = (char*)d_ws;
  float* partial = (float*)ws;                        // 256 floats
  float* linp = (float*)(ws + (64 << 10));            // 4*16384 f32 = 256 KB
  _Float16* Wp = (_Float16*)(ws + (size_t)(4 << 20)); // 1.25 MB at 4 MB
  uint4* Xbt = (uint4*)(ws + (size_t)(8 << 20));      // 32 MB at 8 MB offset

  // every cell of partial/linp/Wp/Xbt is written before read: no memset needed

  mid_fused<<<1024 + 2048, 256, 0, stream>>>(vs, fields, Wp, X, ww, Xbt, linp);
  gram_kc<<<256, 512, 0, stream>>>(Xbt, Wp, partial);
  final_out<<<BTOT / 256, 256, 0, stream>>>(partial, linp, wbias, out);
}

// Round 10
// 67.839 us; speedup vs baseline: 1.8816x; 1.0330x over previous
//
#include <hip/hip_runtime.h>
#include <hip/hip_fp16.h>
#include <math.h>
#include <stdint.h>

#define FDIM 1024
#define BTOT 16384
#define EDIM 64
#define NFLD 32
#define NPANEL 4            // 4 panels of 256 cols
#define NPAIRS 10           // upper-tri panel pairs

typedef _Float16 half8 __attribute__((ext_vector_type(8)));
typedef __fp16 fp16x2 __attribute__((ext_vector_type(2)));
typedef float f32x4 __attribute__((ext_vector_type(4)));

// single-instruction f32x2 -> packed f16x2 (v_cvt_pkrtz_f16_f32)
__device__ __forceinline__ uint32_t pk2(float a, float b){
  fp16x2 h = __builtin_amdgcn_cvt_pkrtz(a, b);
  return __builtin_bit_cast(uint32_t, h);
}

__device__ __forceinline__ void gload16(const void* g, void* l){
  __builtin_amdgcn_global_load_lds((const __attribute__((address_space(1))) void*)g,
                                   (__attribute__((address_space(3))) void*)l,
                                   16, 0, 0);
}

// pair index for ti<=tj: (0,0)=0 (0,1)=1 (0,2)=2 (0,3)=3 (1,1)=4 ... (3,3)=9
__device__ __forceinline__ int pairId(int ti, int tj){
  return ti * NPANEL - (ti * (ti + 1)) / 2 + tj;
}

// ---------------------------------------------------------------------------
// mid_fused: blockIdx.x < 2048  -> transpose path (X f32 -> fp16 chunk
//            layout) + linear-term partials. ZERO LDS on this path: scalar
//            reads put col l+64i in lane l directly, so chunk stores are
//            fully coalesced (1KB/instr) with no LDS bounce.
//            blockIdx.x >= 2048 -> W2 path: in-block field bucketing, field-
//            pair GEMM-lets with 32-row x 64-col (+4 pad) fp32 LDS tiles,
//            storing the gram-ready fp16 Wp layout.
// Kernel LDS ~22 KB -> 6 blocks/CU so transpose waves can stream HBM.
// ---------------------------------------------------------------------------
__global__ __launch_bounds__(256, 6) void mid_fused(
    const float* __restrict__ vs, const int* __restrict__ fields,
    _Float16* __restrict__ Wp,
    const float* __restrict__ X, const float* __restrict__ w,
    uint4* __restrict__ Xbt, float* __restrict__ linp){
  const int t = threadIdx.x;

  if (blockIdx.x < 2048){
    // ------------------- transpose + linear path (no LDS) -------------------
    const int bx = blockIdx.x;
    const int p  = bx & 3;                 // panel
    const int kb = bx >> 2;                // 0..511 (32-row chunk)
    const int ro = t >> 6;                 // wave = oct within chunk
    const int l  = t & 63;
    const int og = kb * 4 + ro;            // global k-oct
    const int k0 = og * 8;
    const int c0 = p * 256;

    // lane l holds cols c0 + l + 64*i  (i=0..3), rows k0..k0+7
    float xs[8][4];
#pragma unroll
    for (int r = 0; r < 8; ++r)
#pragma unroll
      for (int i = 0; i < 4; ++i)
        xs[r][i] = X[(size_t)(k0 + r) * FDIM + c0 + i * 64 + l];

    float wv[4];
#pragma unroll
    for (int i = 0; i < 4; ++i) wv[i] = w[c0 + i * 64 + l];
#pragma unroll
    for (int r = 0; r < 8; ++r){
      float lp = xs[r][0] * wv[0] + xs[r][1] * wv[1]
               + xs[r][2] * wv[2] + xs[r][3] * wv[3];
#pragma unroll
      for (int off = 32; off; off >>= 1) lp += __shfl_xor(lp, off, 64);
      if (l == 0) linp[(size_t)p * BTOT + k0 + r] = lp;
    }

    uint4* dst = Xbt + ((size_t)p * 2048 + og) * 256;
#pragma unroll
    for (int i = 0; i < 4; ++i){
      uint4 ch;                            // chunk = 8 k's of col c0+l+64i
      ch.x = pk2(xs[0][i], xs[1][i]);
      ch.y = pk2(xs[2][i], xs[3][i]);
      ch.z = pk2(xs[4][i], xs[5][i]);
      ch.w = pk2(xs[6][i], xs[7][i]);
      dst[l + 64 * i] = ch;                // coalesced 1KB per instruction
    }
    return;
  }

  // --------------- W2 path (merged prep, 32-row x 64-col tiles) ---------------
  __shared__ float Si[32][68];   // 64 cols (EDIM) + 4 pad
  __shared__ float Sj[32][68];
  __shared__ int gI[32], gJ[32];
  __shared__ int cnt[NFLD], pos[NFLD], off[NFLD + 1];
  __shared__ int permS[FDIM];

  if (t < NFLD) cnt[t] = 0;
  __syncthreads();
#pragma unroll
  for (int r = 0; r < 4; ++r) atomicAdd(&cnt[fields[t + 256 * r]], 1);
  __syncthreads();
  if (t == 0){
    int s = 0;
    for (int i = 0; i < NFLD; ++i){ off[i] = s; s += cnt[i]; }
    off[NFLD] = s;
  }
  __syncthreads();
  if (t < NFLD) pos[t] = off[t];
  __syncthreads();
#pragma unroll
  for (int r = 0; r < 4; ++r){
    const int idx = t + 256 * r;
    const int p = atomicAdd(&pos[fields[idx]], 1);
    permS[p] = idx;
  }
  __syncthreads();

  const int a = (blockIdx.x - 2048) >> 5, b = (blockIdx.x - 2048) & 31;
  const int oa = off[a], na = off[a + 1] - oa;
  const int ob = off[b], nb_ = off[b + 1] - ob;
  if (na == 0 || nb_ == 0) return;
  for (int ia0 = 0; ia0 < na; ia0 += 32){
    const int nac = min(32, na - ia0);
    for (int jb0 = 0; jb0 < nb_; jb0 += 32){
      const int nbc = min(32, nb_ - jb0);
      __syncthreads();
      if (t < 32){
        gI[t] = (t < nac) ? permS[oa + ia0 + t] : 0;
        gJ[t] = (t < nbc) ? permS[ob + jb0 + t] : 0;
      }
      __syncthreads();
#pragma unroll
      for (int rep = 0; rep < 2; ++rep){
        const int lidx = rep * 256 + t;     // 0..511 = 32 rows x 16 float4
        const int r = lidx >> 4, e4 = (lidx & 15) * 4;
        if (r < nac)
          *(float4*)&Si[r][e4] = *(const float4*)(vs + ((size_t)b * FDIM + gI[r]) * EDIM + e4);
        if (r < nbc)
          *(float4*)&Sj[r][e4] = *(const float4*)(vs + ((size_t)a * FDIM + gJ[r]) * EDIM + e4);
      }
      __syncthreads();
      const int jr = t & 31;
      const int ir0 = t >> 5;               // 0..7
      for (int ko = 0; ko * 8 < nac; ++ko){
        const int ir = ko * 8 + ir0;
        if (ir < nac && jr < nbc){
          float dot = 0.f;
#pragma unroll
          for (int e4 = 0; e4 < EDIM; e4 += 4){
            const float4 x = *(const float4*)&Si[ir][e4];
            const float4 y = *(const float4*)&Sj[jr][e4];
            dot += x.x * y.x + x.y * y.y + x.z * y.z + x.w * y.w;
          }
          const int gi = gI[ir], gj = gJ[jr];
          const int pi = gi >> 8, pj = gj >> 8;
          if (pi <= pj){
            const float v = (gj > gi) ? dot : 0.f;
            const int li = gi & 255, lj = gj & 255;
            const int P  = pairId(pi, pj);
            const int w8 = (li >> 7) * 4 + (lj >> 6);
            const int mb = (li >> 4) & 7, r_ = li & 3;
            const int lane = ((li >> 2) & 3) * 16 + (lj & 15);
            const int nbv = (lj >> 4) & 3;
            const size_t o_ = (size_t)(P * 8 + w8) * 8192
                            + (size_t)((mb * 2 + (r_ >> 1)) * 64 + lane) * 8
                            + (r_ & 1) * 4 + nbv;
            Wp[o_] = (_Float16)v;
          }
        }
      }
    }
  }
}

// ---------------------------------------------------------------------------
// gram_kc: 256 blocks (1/CU), each owns ONE 64-row k-chunk. Stages the full
// 4-panel fp16 slice (128 KB LDS, 16 gload16/thread, panel-major issue) and
// computes all 10 panel-pairs from LDS, dotting each P-chunk with Wp
// immediately (sum over k-chunks distributes). Xbt is read EXACTLY ONCE
// (32 MB total). Pair groups gated by counted vmcnt (12/8/4/0) + s_barrier:
// pair (0,0) starts after only panel 0 has landed. Per-wave running W-dot
// partial, block-reduced at the end. No same-address atomics.
// ---------------------------------------------------------------------------
__global__ __launch_bounds__(512, 2) void gram_kc(
    const uint4* __restrict__ Xbt, const _Float16* __restrict__ Wp,
    float* __restrict__ partial){
  __shared__ uint4 lds4[8192];   // [oct(8)][panel(4)][col(256)] = 128 KB
  const int t = threadIdx.x, w = t >> 6, lane = t & 63;
  const int orow = lane >> 4, rl = lane & 15;
  const int wr = w >> 2, wc = w & 3;     // wave sub-tile (2 x 4) of 256x256
  const int b8 = blockIdx.x * 8;         // first k-oct of this chunk

  // issue all staging, panel-major (4 loads per thread per panel)
#pragma unroll
  for (int p = 0; p < NPANEL; ++p)
#pragma unroll
    for (int q = 0; q < 4; ++q){
      const int m = q * 512 + t;
      const int o = m >> 8, c = m & 255;
      gload16(Xbt + ((size_t)p * 2048 + b8 + o) * 256 + c,
              lds4 + o * 1024 + p * 256 + c);
    }

  float wsum = 0.f;

  auto loadB = [&](int tj, half8 (&bf)[2][4]){
#pragma unroll
    for (int s = 0; s < 2; ++s)
#pragma unroll
      for (int nb = 0; nb < 4; ++nb)
        bf[s][nb] = __builtin_bit_cast(half8,
            lds4[(s * 4 + orow) * 1024 + tj * 256 + wc * 64 + nb * 16 + rl]);
  };

  auto body = [&](int ti, int tj, const half8 (&bf)[2][4]){
    f32x4 acc[8][4];
#pragma unroll
    for (int i = 0; i < 8; ++i)
#pragma unroll
      for (int j = 0; j < 4; ++j) acc[i][j] = {0.f, 0.f, 0.f, 0.f};
#pragma unroll
    for (int s = 0; s < 2; ++s)
#pragma unroll
      for (int mb = 0; mb < 8; ++mb){
        const half8 af = __builtin_bit_cast(half8,
            lds4[(s * 4 + orow) * 1024 + ti * 256 + wr * 128 + mb * 16 + rl]);
#pragma unroll
        for (int nb = 0; nb < 4; ++nb)
          acc[mb][nb] = __builtin_amdgcn_mfma_f32_16x16x32_f16(
              af, bf[s][nb], acc[mb][nb], 0, 0, 0);
      }
    // W-dot epilogue: 16 coalesced b128 loads from the pair/wave Wp subtile
    const uint4* wp = (const uint4*)(Wp + (size_t)(pairId(ti, tj) * 8 + w) * 8192);
#pragma unroll
    for (int mb = 0; mb < 8; ++mb)
#pragma unroll
      for (int h = 0; h < 2; ++h){
        const half8 hv = __builtin_bit_cast(half8, wp[(mb * 2 + h) * 64 + lane]);
#pragma unroll
        for (int r2 = 0; r2 < 2; ++r2)
#pragma unroll
          for (int nb = 0; nb < 4; ++nb)
            wsum += (float)hv[r2 * 4 + nb] * acc[mb][nb][2 * h + r2];
      }
  };

#define GRAM_GROUP(G, VM)                                         \
  asm volatile("s_waitcnt vmcnt(" #VM ")" ::: "memory");          \
  __builtin_amdgcn_s_barrier();                                   \
  {                                                               \
    half8 bf[2][4];                                               \
    loadB(G, bf);                                                 \
    _Pragma("unroll 1")                                           \
    for (int ti = 0; ti <= (G); ++ti) body(ti, (G), bf);          \
  }

  GRAM_GROUP(0, 12)
  GRAM_GROUP(1, 8)
  GRAM_GROUP(2, 4)
  GRAM_GROUP(3, 0)
#undef GRAM_GROUP

  // block reduce: wave-reduce, then cross-wave via LDS (reuse, post-barrier)
#pragma unroll
  for (int off = 32; off; off >>= 1) wsum += __shfl_xor(wsum, off, 64);
  __syncthreads();
  float* red = (float*)lds4;
  if (lane == 0) red[w] = wsum;
  __syncthreads();
  if (t == 0){
    float s = 0.f;
#pragma unroll
    for (int i = 0; i < 8; ++i) s += red[i];
    partial[blockIdx.x] = s;
  }
}

// ---------------------------------------------------------------------------
// final_out: reduce 256 per-block gram partials (redundantly per block,
// L2-hot), add 4 linear partials per row, sigmoid.
// ---------------------------------------------------------------------------
__global__ __launch_bounds__(256) void final_out(
    const float* __restrict__ partial, const float* __restrict__ linp,
    const float* __restrict__ wb, float* __restrict__ out){
  __shared__ float red[256];
  const int t = threadIdx.x;
  red[t] = partial[t];
  __syncthreads();
  for (int off = 128; off; off >>= 1){
    if (t < off) red[t] += red[t + off];
    __syncthreads();
  }
  const float stot = red[0] + wb[0];
  const int i = blockIdx.x * 256 + t;
  float z = stot;
#pragma unroll
  for (int p = 0; p < NPANEL; ++p) z += linp[(size_t)p * BTOT + i];
  out[i] = 1.f / (1.f + expf(-z));
}

// ---------------------------------------------------------------------------
extern "C" void kernel_launch(void* const* d_in, const int* in_sizes, int n_in,
                              void* d_out, int out_size, void* d_ws,
                              size_t ws_size, hipStream_t stream) {
  const float* X      = (const float*)d_in[0];  // [B, F]
  const int* fields   = (const int*)d_in[1];    // [F]
  const float* ww     = (const float*)d_in[2];  // [1, F]
  const float* wbias  = (const float*)d_in[3];  // [1]
  const float* vs     = (const float*)d_in[4];  // [NF, F, E]
  float* out          = (float*)d_out;          // [B, 1]

  char* ws = (char*)d_ws;
  float* partial = (float*)ws;                        // 256 floats
  float* linp = (float*)(ws + (64 << 10));            // 4*16384 f32 = 256 KB
  _Float16* Wp = (_Float16*)(ws + (size_t)(4 << 20)); // 1.25 MB at 4 MB
  uint4* Xbt = (uint4*)(ws + (size_t)(8 << 20));      // 32 MB at 8 MB offset

  // every cell of partial/linp/Wp/Xbt is written before read: no memset needed

  mid_fused<<<2048 + 1024, 256, 0, stream>>>(vs, fields, Wp, X, ww, Xbt, linp);
  gram_kc<<<256, 512, 0, stream>>>(Xbt, Wp, partial);
  final_out<<<BTOT / 256, 256, 0, stream>>>(partial, linp, wbias, out);
}